// Round 4
// baseline (263.292 us; speedup 1.0000x reference)
//
#include <hip/hip_runtime.h>

// Decay-based linear recurrent scan:  S_t = d*S_{t-1} + (1-d)*kv_t ; out_t = q_t*S_t
// fp32, (T,B,H,V,D) = (128,16,8,25,64).
//
// Round-6 design: single-kernel chunked scan — buy in-flight bytes with WAVES,
// not per-wave pipeline depth.
//   History: v4/v6 (C++ pipeline, with/without sched_barrier) were both collapsed
//   by the compiler to ~2 loads in flight (VGPR_Count 44/48 vs the 64+ the buffers
//   need) -> 2.0 TB/s latency-bound at 2.2 waves/CU. v5 (raw-asm loads) crashed.
//   The harness fill kernel sustains 6.8 TB/s at 9% occupancy, so the chip only
//   needs ~10 KB/CU in flight; we get it via TLP: split T=128 into 8 chunks of 16
//   (the recurrence is linear), all chunks of a channel-group in ONE block.
//     wave w of 8: local scan of chunk w from S=0 (kv chunk held in 64 VGPRs)
//     -> publish B_w via LDS -> __syncthreads -> S_in = Horner fold of B_{w'<w}
//     with A = d^16 -> replay chunk against q, store out.
//   kv read once, q read once, out written once (310 MB minimum), no workspace,
//   one launch. 800 blocks x 8 waves = 6400 waves = 16-25 resident waves/CU.
//   Even 2 loads in flight per wave then gives >30 KB/CU in flight.
//   Numerics: same chunk reassociation as the round-1 two-pass version
//   (passed, absmax 2e-3); within-chunk math is the identical fma chain.

#define T_DIM 128
#define CH    204800            // B*H*V*D
#define CH4   (CH / 4)          // 51200 float4 channels
#define VD    (25 * 64)         // V*D
#define NW    8                 // waves per block = number of T-chunks
#define LCH   (T_DIM / NW)      // 16 steps per chunk

typedef float f32x4 __attribute__((ext_vector_type(4)));

__global__ __launch_bounds__(NW * 64) void sss_scan_v7(
    const f32x4* __restrict__ q,
    const f32x4* __restrict__ kv,
    const float* __restrict__ decay,
    f32x4* __restrict__ out)
{
    __shared__ f32x4 Blds[NW][64];          // 8 KB: per-chunk contributions

    const int w    = threadIdx.x >> 6;      // wave id = chunk id
    const int lane = threadIdx.x & 63;
    const int ci   = blockIdx.x * 64 + lane;   // float4-channel index
    const int e0   = ci * 4;
    const int dd   = e0 & 63;               // d-offset within D=64 (multiple of 4)
    const int h    = (e0 / VD) & 7;         // head index

    const f32x4 d   = *(const f32x4*)(decay + h * 64 + dd);
    const f32x4 omd = 1.0f - d;

    const size_t tbase = (size_t)w * LCH;
    const f32x4* __restrict__ kp = kv  + tbase * CH4 + ci;
    const f32x4* __restrict__ qp = q   + tbase * CH4 + ci;
    f32x4*       __restrict__ op = out + tbase * CH4 + ci;

    // ---- phase 1: load kv chunk into registers (16 independent 16B loads) ----
    f32x4 kr[LCH];
    #pragma unroll
    for (int j = 0; j < LCH; ++j)
        kr[j] = kp[(size_t)j * CH4];

    // local scan from 0 -> chunk contribution B_w
    f32x4 B = (f32x4)0.0f;
    #pragma unroll
    for (int j = 0; j < LCH; ++j) {
        B[0] = fmaf(d[0], B[0], omd[0] * kr[j][0]);
        B[1] = fmaf(d[1], B[1], omd[1] * kr[j][1]);
        B[2] = fmaf(d[2], B[2], omd[2] * kr[j][2]);
        B[3] = fmaf(d[3], B[3], omd[3] * kr[j][3]);
    }
    Blds[w][lane] = B;
    __syncthreads();

    // ---- chunk-prefix fold: S_in = sum_{w'<w} A^(w-1-w') B_w',  A = d^16 ----
    f32x4 A = d * d;     // d^2
    A = A * A;           // d^4
    A = A * A;           // d^8
    A = A * A;           // d^16
    f32x4 S = (f32x4)0.0f;
    for (int wp = 0; wp < w; ++wp) {        // wave-uniform trip count
        const f32x4 Bp = Blds[wp][lane];
        S[0] = fmaf(A[0], S[0], Bp[0]);
        S[1] = fmaf(A[1], S[1], Bp[1]);
        S[2] = fmaf(A[2], S[2], Bp[2]);
        S[3] = fmaf(A[3], S[3], Bp[3]);
    }

    // ---- phase 2: replay chunk with true S_in, multiply by q, store ----
    #pragma unroll
    for (int j = 0; j < LCH; ++j) {
        const f32x4 qq = qp[(size_t)j * CH4];
        S[0] = fmaf(d[0], S[0], omd[0] * kr[j][0]);
        S[1] = fmaf(d[1], S[1], omd[1] * kr[j][1]);
        S[2] = fmaf(d[2], S[2], omd[2] * kr[j][2]);
        S[3] = fmaf(d[3], S[3], omd[3] * kr[j][3]);
        f32x4 o = qq * S;
        __builtin_nontemporal_store(o, op + (size_t)j * CH4);  // out: no reuse
    }
}

extern "C" void kernel_launch(void* const* d_in, const int* in_sizes, int n_in,
                              void* d_out, int out_size, void* d_ws, size_t ws_size,
                              hipStream_t stream) {
    const f32x4* q     = (const f32x4*)d_in[0];
    const f32x4* kv    = (const f32x4*)d_in[1];
    const float* decay = (const float*)d_in[2];
    f32x4* out = (f32x4*)d_out;

    const int blocks = CH4 / 64;   // 800 blocks x 512 threads = 6400 waves
    sss_scan_v7<<<blocks, NW * 64, 0, stream>>>(q, kv, decay, out);
}

// Round 5
// 261.283 us; speedup vs baseline: 1.0077x; 1.0077x over previous
//
#include <hip/hip_runtime.h>

// Decay-based linear recurrent scan:  S_t = d*S_{t-1} + (1-d)*kv_t ; out_t = q_t*S_t
// fp32, (T,B,H,V,D) = (128,16,8,25,64).
//
// Round-7 design: chunked scan (v7 structure) + 2 channel-chains per thread so
// each wave's per-t visit is a 2 KB contiguous run per array (2x v7's 1 KB).
//   Evidence trail: v4/v6 (MLP attempts) and v7 (TLP: occupancy 6.8%->31%) ALL
//   land at 2.0 +/- 0.05 TB/s -> in-flight bytes are NOT the limit; the memory
//   system retires this pattern (1 KB runs strided by 800 KB) at a fixed rate.
//   Harness fill (sequential) hits 6.8 TB/s on the same chip. So: lengthen the
//   contiguous runs. 64 lanes x 16 B x 2 chains = 2 KB per array per t-visit,
//   issued as back-to-back dwordx4 instructions.
//   Structure per block (512 thr = 8 waves, f4-channels [b*128, b*128+128)):
//     wave w = T-chunk [16w, 16w+16): local kv scan from 0 -> B_w -> LDS
//     -> __syncthreads -> S_in = Horner fold of B_{w'<w} with A = d^16
//     -> replay chunk (kv re-read; LLC-resident, v7-verified no FETCH increase),
//        out = q * S, plain stores (NT bought nothing: FETCH identical r0 vs r4).
//   400 blocks x 8 waves = 3200 waves (~12/CU). Numerics identical to v7 (passed,
//   absmax 2e-3): same chunk reassociation, same fma chains.

#define T_DIM 128
#define CH4   51200             // float4 channels = B*H*V*D/4
#define VD    1600              // V*D (scalars)
#define NW    8                 // waves per block = number of T-chunks
#define LCH   (T_DIM / NW)      // 16 steps per chunk
#define CPT   2                 // channel-chains per thread
#define BCH   (64 * CPT)        // f4-channels per block = 128
#define NBLK  (CH4 / BCH)       // 400 blocks

typedef float f32x4 __attribute__((ext_vector_type(4)));

__global__ __launch_bounds__(NW * 64, 4) void sss_scan_v8(
    const f32x4* __restrict__ q,
    const f32x4* __restrict__ kv,
    const float* __restrict__ decay,
    f32x4* __restrict__ out)
{
    __shared__ f32x4 Blds[NW][BCH];         // 16 KB: per-chunk contributions

    const int w     = threadIdx.x >> 6;     // wave id = chunk id
    const int lane  = threadIdx.x & 63;
    const int cbase = blockIdx.x * BCH + lane;   // chain-0 f4-channel

    // per-chain decay (chain c at ci = cbase + 64c; 64 f4 = 256 scalars, so the
    // D-offset is lane-only; the head h can differ per chain/lane)
    f32x4 d2[CPT], omd2[CPT];
    #pragma unroll
    for (int c = 0; c < CPT; ++c) {
        const int ci = cbase + c * 64;
        const int e0 = ci * 4;
        const int dd = e0 & 63;
        const int h  = (e0 / VD) & 7;
        d2[c]   = *(const f32x4*)(decay + h * 64 + dd);
        omd2[c] = 1.0f - d2[c];
    }

    const size_t tb = (size_t)w * LCH;

    // ---- phase 1: local scan of this wave's kv chunk from S=0 ----
    f32x4 B[CPT];
    #pragma unroll
    for (int c = 0; c < CPT; ++c) B[c] = (f32x4)0.0f;

    #pragma unroll
    for (int j = 0; j < LCH; ++j) {
        f32x4 kk[CPT];
        #pragma unroll
        for (int c = 0; c < CPT; ++c)       // 2 adjacent 1 KB loads = 2 KB run
            kk[c] = kv[(tb + j) * CH4 + cbase + c * 64];
        #pragma unroll
        for (int c = 0; c < CPT; ++c) {
            B[c][0] = fmaf(d2[c][0], B[c][0], omd2[c][0] * kk[c][0]);
            B[c][1] = fmaf(d2[c][1], B[c][1], omd2[c][1] * kk[c][1]);
            B[c][2] = fmaf(d2[c][2], B[c][2], omd2[c][2] * kk[c][2]);
            B[c][3] = fmaf(d2[c][3], B[c][3], omd2[c][3] * kk[c][3]);
        }
    }
    #pragma unroll
    for (int c = 0; c < CPT; ++c)
        Blds[w][c * 64 + lane] = B[c];
    __syncthreads();

    // ---- chunk-prefix fold: S_in = sum_{w'<w} A^(w-1-w') B_w', A = d^16 ----
    f32x4 S[CPT];
    #pragma unroll
    for (int c = 0; c < CPT; ++c) {
        f32x4 A = d2[c] * d2[c];   // d^2
        A = A * A;                 // d^4
        A = A * A;                 // d^8
        A = A * A;                 // d^16
        f32x4 s = (f32x4)0.0f;
        for (int wp = 0; wp < w; ++wp) {    // wave-uniform trip count
            const f32x4 Bp = Blds[wp][c * 64 + lane];
            s[0] = fmaf(A[0], s[0], Bp[0]);
            s[1] = fmaf(A[1], s[1], Bp[1]);
            s[2] = fmaf(A[2], s[2], Bp[2]);
            s[3] = fmaf(A[3], s[3], Bp[3]);
        }
        S[c] = s;
    }

    // ---- phase 2: replay chunk with true S_in; out = q * S ----
    #pragma unroll
    for (int j = 0; j < LCH; ++j) {
        f32x4 kk[CPT], qq[CPT];
        #pragma unroll
        for (int c = 0; c < CPT; ++c)
            kk[c] = kv[(tb + j) * CH4 + cbase + c * 64];
        #pragma unroll
        for (int c = 0; c < CPT; ++c)
            qq[c] = q[(tb + j) * CH4 + cbase + c * 64];
        #pragma unroll
        for (int c = 0; c < CPT; ++c) {
            S[c][0] = fmaf(d2[c][0], S[c][0], omd2[c][0] * kk[c][0]);
            S[c][1] = fmaf(d2[c][1], S[c][1], omd2[c][1] * kk[c][1]);
            S[c][2] = fmaf(d2[c][2], S[c][2], omd2[c][2] * kk[c][2]);
            S[c][3] = fmaf(d2[c][3], S[c][3], omd2[c][3] * kk[c][3]);
            f32x4 o;
            o = qq[c] * S[c];
            out[(tb + j) * CH4 + cbase + c * 64] = o;
        }
    }
}

extern "C" void kernel_launch(void* const* d_in, const int* in_sizes, int n_in,
                              void* d_out, int out_size, void* d_ws, size_t ws_size,
                              hipStream_t stream) {
    const f32x4* q     = (const f32x4*)d_in[0];
    const f32x4* kv    = (const f32x4*)d_in[1];
    const float* decay = (const float*)d_in[2];
    f32x4* out = (f32x4*)d_out;

    sss_scan_v8<<<NBLK, NW * 64, 0, stream>>>(q, kv, decay, out);
}